// Round 1
// baseline (751.050 us; speedup 1.0000x reference)
//
#include <hip/hip_runtime.h>

// FM-CTR forward: one 32-lane half-wave per batch sample.
// Each lane owns 4 of the 128 embedding dims (float4 per gather row).
// 26 gathers of 512B rows dominate -> memory-bound; target ~35us at 6.3 TB/s.

constexpr int N_TABLES  = 26;
constexpr int VOCAB     = 50000;
constexpr int EMBED_DIM = 128;
constexpr int DENSE_DIM = 13;
constexpr int BATCH     = 16384;

__global__ __launch_bounds__(256) void fmctr_kernel(
    const float* __restrict__ dense_x,     // (BATCH, 13)
    const int*   __restrict__ discrete_x,  // (BATCH, 26) int32
    const float* __restrict__ emb,         // (26, 50000, 128)
    const float* __restrict__ dense_w,     // (128, 13)
    const float* __restrict__ dense_b,     // (128,)
    float*       __restrict__ out)         // (BATCH,)
{
    const int tid  = blockIdx.x * 256 + threadIdx.x;
    const int b    = tid >> 5;              // sample id: one half-wave per sample
    const int lane = threadIdx.x & 31;      // 32 lanes cover 128 dims as float4

    // ---- load the 26 indices (uniform across the half-wave; L1 broadcasts) ----
    const int* idxp = discrete_x + (long)b * N_TABLES;
    int idx[N_TABLES];
#pragma unroll
    for (int t = 0; t < N_TABLES; ++t) idx[t] = idxp[t];

    // ---- gather + accumulate sum and sum-of-squares for this lane's 4 dims ----
    float s[4] = {0.f, 0.f, 0.f, 0.f};
    float q[4] = {0.f, 0.f, 0.f, 0.f};

#pragma unroll
    for (int t = 0; t < N_TABLES; ++t) {
        const float4 v = *(const float4*)(emb
            + ((long)t * VOCAB + idx[t]) * EMBED_DIM + lane * 4);
        s[0] += v.x; s[1] += v.y; s[2] += v.z; s[3] += v.w;
        q[0] += v.x * v.x; q[1] += v.y * v.y;
        q[2] += v.z * v.z; q[3] += v.w * v.w;
    }

    // ---- dense embedding for dims j = lane*4 .. lane*4+3 (inline tiny GEMV) ----
    float xv[DENSE_DIM];
    const float* xp = dense_x + (long)b * DENSE_DIM;
#pragma unroll
    for (int k = 0; k < DENSE_DIM; ++k) xv[k] = xp[k];

    float fm = 0.f;
    const int j0 = lane * 4;
#pragma unroll
    for (int c = 0; c < 4; ++c) {
        const float* wr = dense_w + (long)(j0 + c) * DENSE_DIM;
        float d = dense_b[j0 + c];
#pragma unroll
        for (int k = 0; k < DENSE_DIM; ++k) d += xv[k] * wr[k];
        const float ss = s[c] + d;
        const float qq = q[c] + d * d;
        fm += 0.5f * (ss * ss - qq);
    }

    // ---- reduce fm across the 32 lanes of this half-wave ----
    // xor masks 1..16 stay within each 32-lane half of the wave64.
#pragma unroll
    for (int m = 16; m >= 1; m >>= 1)
        fm += __shfl_xor(fm, m, 64);

    if (lane == 0) out[b] = fm;
}

extern "C" void kernel_launch(void* const* d_in, const int* in_sizes, int n_in,
                              void* d_out, int out_size, void* d_ws, size_t ws_size,
                              hipStream_t stream) {
    const float* dense_x    = (const float*)d_in[0];
    const int*   discrete_x = (const int*)  d_in[1];
    const float* emb        = (const float*)d_in[2];
    const float* dense_w    = (const float*)d_in[3];
    const float* dense_b    = (const float*)d_in[4];
    float*       out        = (float*)d_out;

    // 256 threads = 8 half-waves = 8 samples per block
    const int blocks = (BATCH * 32) / 256;   // 2048
    fmctr_kernel<<<blocks, 256, 0, stream>>>(dense_x, discrete_x, emb,
                                             dense_w, dense_b, out);
}

// Round 2
// 748.686 us; speedup vs baseline: 1.0032x; 1.0032x over previous
//
#include <hip/hip_runtime.h>

// FM-CTR forward: one 32-lane half-wave per batch sample.
// Each lane owns 4 of the 128 embedding dims (float4 per gather row).
// Gather of 26 random 512B rows/sample (218 MB total) dominates.
// R2: stage gathers in 2 batches of 13 float4 loads to maximize
// outstanding vmem requests (memory-level parallelism A/B test).

constexpr int N_TABLES  = 26;
constexpr int VOCAB     = 50000;
constexpr int EMBED_DIM = 128;
constexpr int DENSE_DIM = 13;
constexpr int BATCH     = 16384;
constexpr int BATCH_LD  = 13;   // gathers in flight per batch

__global__ __launch_bounds__(256, 4) void fmctr_kernel(
    const float* __restrict__ dense_x,     // (BATCH, 13)
    const int*   __restrict__ discrete_x,  // (BATCH, 26) int32
    const float* __restrict__ emb,         // (26, 50000, 128)
    const float* __restrict__ dense_w,     // (128, 13)
    const float* __restrict__ dense_b,     // (128,)
    float*       __restrict__ out)         // (BATCH,)
{
    const int tid  = blockIdx.x * 256 + threadIdx.x;
    const int b    = tid >> 5;              // sample id: one half-wave per sample
    const int lane = threadIdx.x & 31;      // 32 lanes cover 128 dims as float4

    // ---- load the 26 indices (uniform across the half-wave; L1 broadcasts) ----
    const int* idxp = discrete_x + (long)b * N_TABLES;
    int idx[N_TABLES];
#pragma unroll
    for (int t = 0; t < N_TABLES; ++t) idx[t] = idxp[t];

    // ---- gather + accumulate sum and sum-of-squares for this lane's 4 dims ----
    const float* base = emb + (size_t)lane * 4;
    float s[4] = {0.f, 0.f, 0.f, 0.f};
    float q[4] = {0.f, 0.f, 0.f, 0.f};

#pragma unroll
    for (int t0 = 0; t0 < N_TABLES; t0 += BATCH_LD) {
        float4 v[BATCH_LD];
        // issue all 13 gathers back-to-back (no dependent use in between)
#pragma unroll
        for (int j = 0; j < BATCH_LD; ++j) {
            const int t = t0 + j;
            v[j] = *(const float4*)(base + ((size_t)t * VOCAB + idx[t]) * EMBED_DIM);
        }
        // then accumulate
#pragma unroll
        for (int j = 0; j < BATCH_LD; ++j) {
            s[0] += v[j].x; s[1] += v[j].y; s[2] += v[j].z; s[3] += v[j].w;
            q[0] += v[j].x * v[j].x; q[1] += v[j].y * v[j].y;
            q[2] += v[j].z * v[j].z; q[3] += v[j].w * v[j].w;
        }
    }

    // ---- dense embedding for dims j = lane*4 .. lane*4+3 (inline tiny GEMV) ----
    float xv[DENSE_DIM];
    const float* xp = dense_x + (long)b * DENSE_DIM;
#pragma unroll
    for (int k = 0; k < DENSE_DIM; ++k) xv[k] = xp[k];

    float fm = 0.f;
    const int j0 = lane * 4;
#pragma unroll
    for (int c = 0; c < 4; ++c) {
        const float* wr = dense_w + (long)(j0 + c) * DENSE_DIM;
        float d = dense_b[j0 + c];
#pragma unroll
        for (int k = 0; k < DENSE_DIM; ++k) d += xv[k] * wr[k];
        const float ss = s[c] + d;
        const float qq = q[c] + d * d;
        fm += 0.5f * (ss * ss - qq);
    }

    // ---- reduce fm across the 32 lanes of this half-wave ----
    // xor masks 1..16 stay within each 32-lane half of the wave64.
#pragma unroll
    for (int m = 16; m >= 1; m >>= 1)
        fm += __shfl_xor(fm, m, 64);

    if (lane == 0) out[b] = fm;
}

extern "C" void kernel_launch(void* const* d_in, const int* in_sizes, int n_in,
                              void* d_out, int out_size, void* d_ws, size_t ws_size,
                              hipStream_t stream) {
    const float* dense_x    = (const float*)d_in[0];
    const int*   discrete_x = (const int*)  d_in[1];
    const float* emb        = (const float*)d_in[2];
    const float* dense_w    = (const float*)d_in[3];
    const float* dense_b    = (const float*)d_in[4];
    float*       out        = (float*)d_out;

    // 256 threads = 8 half-waves = 8 samples per block
    const int blocks = (BATCH * 32) / 256;   // 2048
    fmctr_kernel<<<blocks, 256, 0, stream>>>(dense_x, discrete_x, emb,
                                             dense_w, dense_b, out);
}